// Round 1
// baseline (281.431 us; speedup 1.0000x reference)
//
#include <hip/hip_runtime.h>

// QFD2Loss: mean over B rows of Q A Q^T, Q = D - softmax(logit), A[j,k]=1-|j-k|/31.
// Identity: QAQ^T = S^2 - (2S/31)*sum_{t<31} P_t + (2/31)*sum_{t<31} P_t^2,
// P_t = prefix sums of Q, S = total sum (kept for exactness; ~1e-7 numerically).
// Layout: 8 lanes per row, each lane owns 4 consecutive elements (one float4).
// Wave (64 lanes) covers 8 rows = 1 KiB per array per iteration, fully coalesced.

#define L_BINS 32

__global__ void qfd2_init(double* acc) {
    if (threadIdx.x == 0 && blockIdx.x == 0) *acc = 0.0;
}

__global__ __launch_bounds__(256) void qfd2_main(const float* __restrict__ logit,
                                                 const float* __restrict__ D,
                                                 double* __restrict__ acc,
                                                 int n_groups) {  // n_groups = B/8
    const int tid     = blockIdx.x * blockDim.x + threadIdx.x;
    const int lane    = threadIdx.x & 63;
    const int wave    = tid >> 6;
    const int n_waves = (gridDim.x * blockDim.x) >> 6;
    const int c       = lane & 7;  // lane-in-row (8 lanes/row)

    float acc_v = 0.0f;
    const float k31 = 2.0f / 31.0f;

    for (int g = wave; g < n_groups; g += n_waves) {
        const size_t base = (size_t)g * 256 + (size_t)lane * 4;
        const float4 z = *(const float4*)(logit + base);
        const float4 d = *(const float4*)(D + base);

        // --- softmax over the 8-lane row group ---
        float m = fmaxf(fmaxf(z.x, z.y), fmaxf(z.z, z.w));
        m = fmaxf(m, __shfl_xor(m, 1));
        m = fmaxf(m, __shfl_xor(m, 2));
        m = fmaxf(m, __shfl_xor(m, 4));

        float e0 = __expf(z.x - m), e1 = __expf(z.y - m);
        float e2 = __expf(z.z - m), e3 = __expf(z.w - m);
        float s = e0 + e1 + e2 + e3;
        s += __shfl_xor(s, 1);
        s += __shfl_xor(s, 2);
        s += __shfl_xor(s, 4);
        const float rs = 1.0f / s;

        // --- Q = D - p, lane-local prefix sums ---
        const float q0 = d.x - e0 * rs;
        const float q1 = d.y - e1 * rs;
        const float q2 = d.z - e2 * rs;
        const float q3 = d.w - e3 * rs;
        const float l0 = q0, l1 = q0 + q1, l2 = l1 + q2, l3 = l2 + q3;

        // inclusive scan of lane sums across the 8 lanes of this row
        float inc = l3, t;
        t = __shfl_up(inc, 1, 8); if (c >= 1) inc += t;
        t = __shfl_up(inc, 2, 8); if (c >= 2) inc += t;
        t = __shfl_up(inc, 4, 8); if (c >= 4) inc += t;
        const float off = inc - l3;          // exclusive prefix for this lane
        const float P0 = off + l0, P1 = off + l1, P2 = off + l2, P3 = inc;
        const float S = __shfl(inc, 7, 8);   // row total (P_31)

        // partial sums over t = 0..30 (exclude global element 31: lane 7's last)
        const bool last = (c == 7);
        const float sumP  = P0 + P1 + P2 + (last ? 0.0f : P3);
        const float sumP2 = P0 * P0 + P1 * P1 + P2 * P2 + (last ? 0.0f : P3 * P3);

        // sum over the row's 8 lanes reconstructs:
        //   (2/31)*SumP2 - (2S/31)*SumP + S^2
        acc_v += k31 * (sumP2 - S * sumP) + 0.125f * S * S;
    }

    // wave reduction (64 lanes)
    for (int msk = 1; msk < 64; msk <<= 1) acc_v += __shfl_xor(acc_v, msk);

    __shared__ float wpart[4];
    const int wib = threadIdx.x >> 6;
    if (lane == 0) wpart[wib] = acc_v;
    __syncthreads();
    if (threadIdx.x == 0) {
        const float bsum = wpart[0] + wpart[1] + wpart[2] + wpart[3];
        atomicAdd(acc, (double)bsum);
    }
}

__global__ void qfd2_finalize(const double* acc, float* out, int rows) {
    if (threadIdx.x == 0 && blockIdx.x == 0)
        out[0] = (float)(*acc / (double)rows);
}

extern "C" void kernel_launch(void* const* d_in, const int* in_sizes, int n_in,
                              void* d_out, int out_size, void* d_ws, size_t ws_size,
                              hipStream_t stream) {
    const float* logit = (const float*)d_in[0];
    const float* D     = (const float*)d_in[1];
    float* out         = (float*)d_out;
    double* acc        = (double*)d_ws;

    const int rows     = in_sizes[0] / L_BINS;   // 1048576
    const int n_groups = rows / 8;               // 131072 wave-groups of 8 rows

    qfd2_init<<<1, 64, 0, stream>>>(acc);
    qfd2_main<<<4096, 256, 0, stream>>>(logit, D, acc, n_groups);
    qfd2_finalize<<<1, 64, 0, stream>>>(acc, out, rows);
}

// Round 2
// 276.852 us; speedup vs baseline: 1.0165x; 1.0165x over previous
//
#include <hip/hip_runtime.h>

// QFD2Loss: mean over B rows of Q A Q^T, Q = D - softmax(logit), A[j,k]=1-|j-k|/31.
// Identity (exact): QAQ^T = S^2 - (2S/31)*sum_{t<31} P_t + (2/31)*sum_{t<31} P_t^2,
// where P_t = prefix sums of Q, S = P_31 (total sum, ~0 but kept for exactness).
//
// R2 layout: ONE LANE = ONE ROW (32 floats = 8 float4 per array per lane).
//  - zero cross-lane ops in the hot path (softmax + scan fully in-register)
//  - 16 independent global_load_dwordx4 per thread -> deep MLP, hides HBM latency
//  - per-block partial sums to d_ws (no init kernel, no global atomics)

#define L_BINS  32
#define NTHREAD 256

__global__ __launch_bounds__(NTHREAD) void qfd2_main(const float* __restrict__ logit,
                                                     const float* __restrict__ D,
                                                     float* __restrict__ partial,
                                                     int rows) {
    const int row = blockIdx.x * NTHREAD + threadIdx.x;
    float res = 0.0f;

    if (row < rows) {
        const float4* zp = (const float4*)(logit + (size_t)row * L_BINS);
        const float4* dp = (const float4*)(D     + (size_t)row * L_BINS);

        float z[L_BINS], d[L_BINS];
        float4* zv = (float4*)z;
        float4* dv = (float4*)d;
#pragma unroll
        for (int i = 0; i < 8; ++i) zv[i] = zp[i];   // 8 independent loads
#pragma unroll
        for (int i = 0; i < 8; ++i) dv[i] = dp[i];   // 8 more, all in flight

        // ---- softmax max (in-register tree) ----
        float t[16];
#pragma unroll
        for (int i = 0; i < 16; ++i) t[i] = fmaxf(z[i], z[i + 16]);
#pragma unroll
        for (int i = 0; i < 8; ++i)  t[i] = fmaxf(t[i], t[i + 8]);
#pragma unroll
        for (int i = 0; i < 4; ++i)  t[i] = fmaxf(t[i], t[i + 4]);
        t[0] = fmaxf(t[0], t[2]);
        t[1] = fmaxf(t[1], t[3]);
        const float m = fmaxf(t[0], t[1]);

        // ---- exp + sum (in-register tree) ----
        float e[L_BINS];
#pragma unroll
        for (int i = 0; i < L_BINS; ++i) e[i] = __expf(z[i] - m);

        float u[16];
#pragma unroll
        for (int i = 0; i < 16; ++i) u[i] = e[i] + e[i + 16];
#pragma unroll
        for (int i = 0; i < 8; ++i)  u[i] = u[i] + u[i + 8];
#pragma unroll
        for (int i = 0; i < 4; ++i)  u[i] = u[i] + u[i + 4];
        const float s  = (u[0] + u[2]) + (u[1] + u[3]);
        const float rs = 1.0f / s;

        // ---- Q = D - p, prefix sums, sum(P), sum(P^2) over t=0..30 ----
        float P = 0.0f, sP = 0.0f, sP2 = 0.0f;
#pragma unroll
        for (int i = 0; i < L_BINS - 1; ++i) {
            P  += d[i] - e[i] * rs;
            sP += P;
            sP2 = fmaf(P, P, sP2);
        }
        P += d[L_BINS - 1] - e[L_BINS - 1] * rs;
        const float S = P;
        res = (2.0f / 31.0f) * (sP2 - S * sP) + S * S;
    }

    // ---- wave + block reduction, one partial per block ----
#pragma unroll
    for (int msk = 1; msk < 64; msk <<= 1) res += __shfl_xor(res, msk);

    __shared__ float wpart[NTHREAD / 64];
    const int wib = threadIdx.x >> 6;
    if ((threadIdx.x & 63) == 0) wpart[wib] = res;
    __syncthreads();
    if (threadIdx.x == 0)
        partial[blockIdx.x] = (wpart[0] + wpart[1]) + (wpart[2] + wpart[3]);
}

__global__ __launch_bounds__(256) void qfd2_fin(const float* __restrict__ partial,
                                                float* __restrict__ out,
                                                int nblocks, int rows) {
    double a = 0.0;
    for (int i = threadIdx.x; i < nblocks; i += 256) a += (double)partial[i];
#pragma unroll
    for (int msk = 1; msk < 64; msk <<= 1) a += __shfl_xor(a, msk);

    __shared__ double wp[4];
    if ((threadIdx.x & 63) == 0) wp[threadIdx.x >> 6] = a;
    __syncthreads();
    if (threadIdx.x == 0)
        out[0] = (float)(((wp[0] + wp[1]) + (wp[2] + wp[3])) / (double)rows);
}

extern "C" void kernel_launch(void* const* d_in, const int* in_sizes, int n_in,
                              void* d_out, int out_size, void* d_ws, size_t ws_size,
                              hipStream_t stream) {
    const float* logit = (const float*)d_in[0];
    const float* D     = (const float*)d_in[1];
    float* out         = (float*)d_out;
    float* partial     = (float*)d_ws;

    const int rows    = in_sizes[0] / L_BINS;            // 1048576
    const int nblocks = (rows + NTHREAD - 1) / NTHREAD;  // 4096

    qfd2_main<<<nblocks, NTHREAD, 0, stream>>>(logit, D, partial, rows);
    qfd2_fin<<<1, 256, 0, stream>>>(partial, out, nblocks, rows);
}

// Round 3
// 275.177 us; speedup vs baseline: 1.0227x; 1.0061x over previous
//
#include <hip/hip_runtime.h>

// QFD2Loss: mean over B rows of Q A Q^T, Q = D - softmax(logit), A[j,k]=1-|j-k|/31.
// Identity (exact): QAQ^T = S^2 - (2S/31)*sum_{t<31} P_t + (2/31)*sum_{t<31} P_t^2,
// P_t = prefix sums of Q, S = P_31.
//
// R3: coalesced global loads + LDS transpose, lane-private row compute.
//  - R2's lane-per-row global loads were address-divergent (64 cachelines per
//    instruction -> VMEM serialization, 100 us with both pipes idle).
//  - Now: block stages a 256-row tile with fully coalesced float4 loads into
//    LDS (row pitch 36 floats = 144 B: bank-quad index (9*row+f)%8 is a lane
//    permutation -> conflict-free at LDS BW bound for both writes and reads).
//  - Compute phase identical to R2: in-register softmax + prefix-sum identity.

#define L_BINS  32
#define NTHREAD 256
#define PAD     36   // floats per row in LDS (144 B; 16B-aligned, breaks bank alignment)

__global__ __launch_bounds__(NTHREAD) void qfd2_main(const float* __restrict__ logit,
                                                     const float* __restrict__ D,
                                                     float* __restrict__ partial) {
    __shared__ float zbuf[NTHREAD * PAD];   // 36 KB
    __shared__ float dbuf[NTHREAD * PAD];   // 36 KB

    const int t = threadIdx.x;
    const size_t tile_f4 = (size_t)blockIdx.x * (NTHREAD * L_BINS / 4);
    const float4* zg = (const float4*)logit + tile_f4;
    const float4* dg = (const float4*)D + tile_f4;

    // ---- coalesced staging: 8 float4 per thread per array, all loads in flight ----
    float4 vz[8], vd[8];
#pragma unroll
    for (int k = 0; k < 8; ++k) vz[k] = zg[k * NTHREAD + t];
#pragma unroll
    for (int k = 0; k < 8; ++k) vd[k] = dg[k * NTHREAD + t];
#pragma unroll
    for (int k = 0; k < 8; ++k) {
        const int p = k * NTHREAD + t;             // float4 index in tile
        *(float4*)&zbuf[(p >> 3) * PAD + (p & 7) * 4] = vz[k];
    }
#pragma unroll
    for (int k = 0; k < 8; ++k) {
        const int p = k * NTHREAD + t;
        *(float4*)&dbuf[(p >> 3) * PAD + (p & 7) * 4] = vd[k];
    }
    __syncthreads();

    // ---- lane-private row compute ----
    float z[L_BINS], d[L_BINS];
#pragma unroll
    for (int f = 0; f < 8; ++f) ((float4*)z)[f] = *(const float4*)&zbuf[t * PAD + f * 4];
#pragma unroll
    for (int f = 0; f < 8; ++f) ((float4*)d)[f] = *(const float4*)&dbuf[t * PAD + f * 4];

    // softmax max (in-register tree)
    float tm[16];
#pragma unroll
    for (int i = 0; i < 16; ++i) tm[i] = fmaxf(z[i], z[i + 16]);
#pragma unroll
    for (int i = 0; i < 8; ++i)  tm[i] = fmaxf(tm[i], tm[i + 8]);
#pragma unroll
    for (int i = 0; i < 4; ++i)  tm[i] = fmaxf(tm[i], tm[i + 4]);
    const float m = fmaxf(fmaxf(tm[0], tm[2]), fmaxf(tm[1], tm[3]));

    // exp + sum
    float e[L_BINS];
#pragma unroll
    for (int i = 0; i < L_BINS; ++i) e[i] = __expf(z[i] - m);
    float u[16];
#pragma unroll
    for (int i = 0; i < 16; ++i) u[i] = e[i] + e[i + 16];
#pragma unroll
    for (int i = 0; i < 8; ++i)  u[i] = u[i] + u[i + 8];
#pragma unroll
    for (int i = 0; i < 4; ++i)  u[i] = u[i] + u[i + 4];
    const float rs = 1.0f / ((u[0] + u[2]) + (u[1] + u[3]));

    // Q = D - p, prefix sums, sum(P), sum(P^2) over t=0..30
    float P = 0.0f, sP = 0.0f, sP2 = 0.0f;
#pragma unroll
    for (int i = 0; i < L_BINS - 1; ++i) {
        P  += d[i] - e[i] * rs;
        sP += P;
        sP2 = fmaf(P, P, sP2);
    }
    P += d[L_BINS - 1] - e[L_BINS - 1] * rs;
    const float S = P;
    float res = (2.0f / 31.0f) * (sP2 - S * sP) + S * S;

    // ---- wave + block reduction, one partial per block ----
#pragma unroll
    for (int msk = 1; msk < 64; msk <<= 1) res += __shfl_xor(res, msk);

    __shared__ float wpart[NTHREAD / 64];
    if ((t & 63) == 0) wpart[t >> 6] = res;
    __syncthreads();
    if (t == 0)
        partial[blockIdx.x] = (wpart[0] + wpart[1]) + (wpart[2] + wpart[3]);
}

__global__ __launch_bounds__(256) void qfd2_fin(const float* __restrict__ partial,
                                                float* __restrict__ out,
                                                int nblocks, int rows) {
    double a = 0.0;
    for (int i = threadIdx.x; i < nblocks; i += 256) a += (double)partial[i];
#pragma unroll
    for (int msk = 1; msk < 64; msk <<= 1) a += __shfl_xor(a, msk);

    __shared__ double wp[4];
    if ((threadIdx.x & 63) == 0) wp[threadIdx.x >> 6] = a;
    __syncthreads();
    if (threadIdx.x == 0)
        out[0] = (float)(((wp[0] + wp[1]) + (wp[2] + wp[3])) / (double)rows);
}

extern "C" void kernel_launch(void* const* d_in, const int* in_sizes, int n_in,
                              void* d_out, int out_size, void* d_ws, size_t ws_size,
                              hipStream_t stream) {
    const float* logit = (const float*)d_in[0];
    const float* D     = (const float*)d_in[1];
    float* out         = (float*)d_out;
    float* partial     = (float*)d_ws;

    const int rows    = in_sizes[0] / L_BINS;  // 1048576 (divisible by 256)
    const int nblocks = rows / NTHREAD;        // 4096

    qfd2_main<<<nblocks, NTHREAD, 0, stream>>>(logit, D, partial);
    qfd2_fin<<<1, 256, 0, stream>>>(partial, out, nblocks, rows);
}

// Round 5
// 253.000 us; speedup vs baseline: 1.1124x; 1.0877x over previous
//
#include <hip/hip_runtime.h>

// QFD2Loss: mean over B rows of Q A Q^T, Q = D - softmax(logit), A[j,k]=1-|j-k|/31.
// Identity (exact): QAQ^T = S^2 - (2S/31)*sum_{t<31} P_t + (2/31)*sum_{t<31} P_t^2,
// P_t = prefix sums of Q, S = P_31.
//
// R5 = R3 (coalesced float4 -> LDS transpose -> lane-private row compute)
//      + NONTEMPORAL global loads (fixed: builtin needs a native ext_vector
//      type, not HIP_vector_type struct).
// Rationale: R1/R2/R3 (shuffle-bound / divergent / coalesced; occupancy
// 14-70%) all pin at ~100 us = 2.7 TB/s effective -- a downstream floor, not
// a CU-side one. Working set == L3 size and is re-dirtied by the harness's
// input-restore copy each replay; suspected memory-side-cache thrash.
// 'nt' loads skip TCC allocation, removing victim-eviction amplification.
// Streamed data has zero reuse, so dropping cacheability costs nothing.

#define L_BINS  32
#define NTHREAD 256
#define PAD     36   // floats per LDS row (144 B): (9*row+f)%8 bank-quad permutation -> conflict-free

typedef float vfloat4 __attribute__((ext_vector_type(4)));

__device__ __forceinline__ vfloat4 nt_load4(const float* p) {
    return __builtin_nontemporal_load((const vfloat4*)p);
}

__global__ __launch_bounds__(NTHREAD) void qfd2_main(const float* __restrict__ logit,
                                                     const float* __restrict__ D,
                                                     float* __restrict__ partial) {
    __shared__ float zbuf[NTHREAD * PAD];   // 36 KB
    __shared__ float dbuf[NTHREAD * PAD];   // 36 KB

    const int t = threadIdx.x;
    const size_t tile_f = (size_t)blockIdx.x * (NTHREAD * L_BINS);
    const float* zg = logit + tile_f;
    const float* dg = D + tile_f;

    // ---- coalesced nontemporal staging: 16 dwordx4-nt loads per thread in flight ----
    vfloat4 vz[8], vd[8];
#pragma unroll
    for (int k = 0; k < 8; ++k) vz[k] = nt_load4(zg + (k * NTHREAD + t) * 4);
#pragma unroll
    for (int k = 0; k < 8; ++k) vd[k] = nt_load4(dg + (k * NTHREAD + t) * 4);
#pragma unroll
    for (int k = 0; k < 8; ++k) {
        const int p = k * NTHREAD + t;             // float4 index in tile
        *(vfloat4*)&zbuf[(p >> 3) * PAD + (p & 7) * 4] = vz[k];
    }
#pragma unroll
    for (int k = 0; k < 8; ++k) {
        const int p = k * NTHREAD + t;
        *(vfloat4*)&dbuf[(p >> 3) * PAD + (p & 7) * 4] = vd[k];
    }
    __syncthreads();

    // ---- lane-private row compute ----
    float z[L_BINS], d[L_BINS];
#pragma unroll
    for (int f = 0; f < 8; ++f) ((vfloat4*)z)[f] = *(const vfloat4*)&zbuf[t * PAD + f * 4];
#pragma unroll
    for (int f = 0; f < 8; ++f) ((vfloat4*)d)[f] = *(const vfloat4*)&dbuf[t * PAD + f * 4];

    // softmax max (in-register tree)
    float tm[16];
#pragma unroll
    for (int i = 0; i < 16; ++i) tm[i] = fmaxf(z[i], z[i + 16]);
#pragma unroll
    for (int i = 0; i < 8; ++i)  tm[i] = fmaxf(tm[i], tm[i + 8]);
#pragma unroll
    for (int i = 0; i < 4; ++i)  tm[i] = fmaxf(tm[i], tm[i + 4]);
    const float m = fmaxf(fmaxf(tm[0], tm[2]), fmaxf(tm[1], tm[3]));

    // exp + sum
    float e[L_BINS];
#pragma unroll
    for (int i = 0; i < L_BINS; ++i) e[i] = __expf(z[i] - m);
    float u[16];
#pragma unroll
    for (int i = 0; i < 16; ++i) u[i] = e[i] + e[i + 16];
#pragma unroll
    for (int i = 0; i < 8; ++i)  u[i] = u[i] + u[i + 8];
#pragma unroll
    for (int i = 0; i < 4; ++i)  u[i] = u[i] + u[i + 4];
    const float rs = 1.0f / ((u[0] + u[2]) + (u[1] + u[3]));

    // Q = D - p, prefix sums, sum(P), sum(P^2) over t=0..30
    float P = 0.0f, sP = 0.0f, sP2 = 0.0f;
#pragma unroll
    for (int i = 0; i < L_BINS - 1; ++i) {
        P  += d[i] - e[i] * rs;
        sP += P;
        sP2 = fmaf(P, P, sP2);
    }
    P += d[L_BINS - 1] - e[L_BINS - 1] * rs;
    const float S = P;
    float res = (2.0f / 31.0f) * (sP2 - S * sP) + S * S;

    // ---- wave + block reduction, one partial per block ----
#pragma unroll
    for (int msk = 1; msk < 64; msk <<= 1) res += __shfl_xor(res, msk);

    __shared__ float wpart[NTHREAD / 64];
    if ((t & 63) == 0) wpart[t >> 6] = res;
    __syncthreads();
    if (t == 0)
        partial[blockIdx.x] = (wpart[0] + wpart[1]) + (wpart[2] + wpart[3]);
}

__global__ __launch_bounds__(256) void qfd2_fin(const float* __restrict__ partial,
                                                float* __restrict__ out,
                                                int nblocks, int rows) {
    double a = 0.0;
    for (int i = threadIdx.x; i < nblocks; i += 256) a += (double)partial[i];
#pragma unroll
    for (int msk = 1; msk < 64; msk <<= 1) a += __shfl_xor(a, msk);

    __shared__ double wp[4];
    if ((threadIdx.x & 63) == 0) wp[threadIdx.x >> 6] = a;
    __syncthreads();
    if (threadIdx.x == 0)
        out[0] = (float)(((wp[0] + wp[1]) + (wp[2] + wp[3])) / (double)rows);
}

extern "C" void kernel_launch(void* const* d_in, const int* in_sizes, int n_in,
                              void* d_out, int out_size, void* d_ws, size_t ws_size,
                              hipStream_t stream) {
    const float* logit = (const float*)d_in[0];
    const float* D     = (const float*)d_in[1];
    float* out         = (float*)d_out;
    float* partial     = (float*)d_ws;

    const int rows    = in_sizes[0] / L_BINS;  // 1048576 (divisible by 256)
    const int nblocks = rows / NTHREAD;        // 4096

    qfd2_main<<<nblocks, NTHREAD, 0, stream>>>(logit, D, partial);
    qfd2_fin<<<1, 256, 0, stream>>>(partial, out, nblocks, rows);
}

// Round 6
// 247.313 us; speedup vs baseline: 1.1380x; 1.0230x over previous
//
#include <hip/hip_runtime.h>

// QFD2Loss: mean over B rows of Q A Q^T, Q = D - softmax(logit), A[j,k]=1-|j-k|/31.
// Identity (exact): QAQ^T = S^2 - (2S/31)*sum_{t<31} P_t + (2/31)*sum_{t<31} P_t^2,
// P_t = prefix sums of Q, S = P_31.
//
// R6 = R5 (coalesced nt float4 -> LDS transpose -> lane-private row compute)
//      + PERSISTENT BLOCKS with register-prefetch double buffering.
// R5 showed fills at 6.8 TB/s (85% peak) while the kernel sat ~75 us vs the
// 43 us floor: the single-shot block lifecycle serializes load and compute
// phases (vmcnt(0) drain at the barrier). Now each block processes 4 tiles;
// tile i+1's 16 nt loads are issued AFTER the barrier pair and overlap tile
// i's entire compute phase -- the waitcnt lands at the NEXT iteration's
// ds_write, by which point compute has covered the latency.

#define L_BINS  32
#define NTHREAD 256
#define PAD     36     // floats per LDS row (144 B): bank-quad (t+f)%8 permutation -> 0 conflicts (measured R3)
#define NBLOCKS 1024   // 4 tiles per block at B=1M; 2 blocks/CU resident (LDS-limited)

typedef float vfloat4 __attribute__((ext_vector_type(4)));

__device__ __forceinline__ vfloat4 nt_load4(const float* p) {
    return __builtin_nontemporal_load((const vfloat4*)p);
}

__global__ __launch_bounds__(NTHREAD) void qfd2_main(const float* __restrict__ logit,
                                                     const float* __restrict__ D,
                                                     float* __restrict__ partial,
                                                     int ntiles) {
    __shared__ float zbuf[NTHREAD * PAD];   // 36 KB
    __shared__ float dbuf[NTHREAD * PAD];   // 36 KB

    const int t = threadIdx.x;
    float acc = 0.0f;

    vfloat4 vz[8], vd[8];
    int g = blockIdx.x;

    if (g < ntiles) {   // prologue: prefetch first tile
        const float* zg = logit + (size_t)g * (NTHREAD * L_BINS);
        const float* dg = D     + (size_t)g * (NTHREAD * L_BINS);
#pragma unroll
        for (int k = 0; k < 8; ++k) vz[k] = nt_load4(zg + (k * NTHREAD + t) * 4);
#pragma unroll
        for (int k = 0; k < 8; ++k) vd[k] = nt_load4(dg + (k * NTHREAD + t) * 4);
    }

    for (; g < ntiles; g += NBLOCKS) {
        // ---- stage prefetched tile into LDS (transposed) ----
#pragma unroll
        for (int k = 0; k < 8; ++k) {
            const int p = k * NTHREAD + t;
            *(vfloat4*)&zbuf[(p >> 3) * PAD + (p & 7) * 4] = vz[k];
        }
#pragma unroll
        for (int k = 0; k < 8; ++k) {
            const int p = k * NTHREAD + t;
            *(vfloat4*)&dbuf[(p >> 3) * PAD + (p & 7) * 4] = vd[k];
        }
        __syncthreads();

        // ---- lane-private row fetch ----
        float z[L_BINS], d[L_BINS];
#pragma unroll
        for (int f = 0; f < 8; ++f) ((vfloat4*)z)[f] = *(const vfloat4*)&zbuf[t * PAD + f * 4];
#pragma unroll
        for (int f = 0; f < 8; ++f) ((vfloat4*)d)[f] = *(const vfloat4*)&dbuf[t * PAD + f * 4];
        __syncthreads();   // all reads done before next iteration's writes

        // ---- prefetch next tile; overlaps the compute below ----
        const int gn = g + NBLOCKS;
        if (gn < ntiles) {
            const float* zg = logit + (size_t)gn * (NTHREAD * L_BINS);
            const float* dg = D     + (size_t)gn * (NTHREAD * L_BINS);
#pragma unroll
            for (int k = 0; k < 8; ++k) vz[k] = nt_load4(zg + (k * NTHREAD + t) * 4);
#pragma unroll
            for (int k = 0; k < 8; ++k) vd[k] = nt_load4(dg + (k * NTHREAD + t) * 4);
        }

        // ---- softmax max (in-register tree) ----
        float tm[16];
#pragma unroll
        for (int i = 0; i < 16; ++i) tm[i] = fmaxf(z[i], z[i + 16]);
#pragma unroll
        for (int i = 0; i < 8; ++i)  tm[i] = fmaxf(tm[i], tm[i + 8]);
#pragma unroll
        for (int i = 0; i < 4; ++i)  tm[i] = fmaxf(tm[i], tm[i + 4]);
        const float m = fmaxf(fmaxf(tm[0], tm[2]), fmaxf(tm[1], tm[3]));

        // ---- exp (in place) + sum ----
#pragma unroll
        for (int i = 0; i < L_BINS; ++i) z[i] = __expf(z[i] - m);
        float u[16];
#pragma unroll
        for (int i = 0; i < 16; ++i) u[i] = z[i] + z[i + 16];
#pragma unroll
        for (int i = 0; i < 8; ++i)  u[i] = u[i] + u[i + 8];
#pragma unroll
        for (int i = 0; i < 4; ++i)  u[i] = u[i] + u[i + 4];
        const float rs = 1.0f / ((u[0] + u[2]) + (u[1] + u[3]));

        // ---- Q = D - p, prefix sums, sum(P), sum(P^2) over t=0..30 ----
        float P = 0.0f, sP = 0.0f, sP2 = 0.0f;
#pragma unroll
        for (int i = 0; i < L_BINS - 1; ++i) {
            P  += d[i] - z[i] * rs;
            sP += P;
            sP2 = fmaf(P, P, sP2);
        }
        P += d[L_BINS - 1] - z[L_BINS - 1] * rs;
        const float S = P;
        acc += (2.0f / 31.0f) * (sP2 - S * sP) + S * S;
    }

    // ---- wave + block reduction, one partial per block ----
#pragma unroll
    for (int msk = 1; msk < 64; msk <<= 1) acc += __shfl_xor(acc, msk);

    __shared__ float wpart[NTHREAD / 64];
    if ((t & 63) == 0) wpart[t >> 6] = acc;
    __syncthreads();
    if (t == 0)
        partial[blockIdx.x] = (wpart[0] + wpart[1]) + (wpart[2] + wpart[3]);
}

__global__ __launch_bounds__(256) void qfd2_fin(const float* __restrict__ partial,
                                                float* __restrict__ out,
                                                int nblocks, int rows) {
    double a = 0.0;
    for (int i = threadIdx.x; i < nblocks; i += 256) a += (double)partial[i];
#pragma unroll
    for (int msk = 1; msk < 64; msk <<= 1) a += __shfl_xor(a, msk);

    __shared__ double wp[4];
    if ((threadIdx.x & 63) == 0) wp[threadIdx.x >> 6] = a;
    __syncthreads();
    if (threadIdx.x == 0)
        out[0] = (float)(((wp[0] + wp[1]) + (wp[2] + wp[3])) / (double)rows);
}

extern "C" void kernel_launch(void* const* d_in, const int* in_sizes, int n_in,
                              void* d_out, int out_size, void* d_ws, size_t ws_size,
                              hipStream_t stream) {
    const float* logit = (const float*)d_in[0];
    const float* D     = (const float*)d_in[1];
    float* out         = (float*)d_out;
    float* partial     = (float*)d_ws;

    const int rows   = in_sizes[0] / L_BINS;  // 1048576
    const int ntiles = rows / NTHREAD;        // 4096

    qfd2_main<<<NBLOCKS, NTHREAD, 0, stream>>>(logit, D, partial, ntiles);
    qfd2_fin<<<1, 256, 0, stream>>>(partial, out, NBLOCKS, rows);
}